// Round 6
// baseline (288.877 us; speedup 1.0000x reference)
//
#include <hip/hip_runtime.h>
#include <hip/hip_fp16.h>

#define CNUM 29
#define HH 256
#define WW 256
#define BB 2
#define KK 7
#define HALO 3
#define TX 32
#define TY 8
#define LW (TX + 2*HALO)   // 38
#define LH (TY + 2*HALO)   // 14
#define NPIX (LH*LW)       // 532
#define HWP (HH*WW)        // 65536

// 1-D normalized Gaussian, sigma=3.0, K=7 (exp(-d^2/18)/sum)
__device__ constexpr float GW[KK] = {
    0.106287146f, 0.140321912f, 0.165770643f, 0.175240699f,
    0.165770643f, 0.140321912f, 0.106287146f};

__device__ __forceinline__ unsigned packh2(float a, float b) {
    __half2 h = __floats2half2_rn(a, b);
    return *reinterpret_cast<unsigned*>(&h);
}
__device__ __forceinline__ float2 unpkh2(unsigned u) {
    __half2 h = *reinterpret_cast<__half2*>(&u);
    return __half22float2(h);
}

// One CRF iteration, 512 threads per 32x8 tile, channel-split halves
// (hf0: ch0-15, hf1: ch16-28+pads). Global q and uh (= -unary fp16) layouts
// are HALF-MAJOR [b][hf][pix][2 x uint4] so every thread reads/writes 32
// contiguous bytes (wave = 2KB contiguous). LDS q tile channel-last fp16,
// chunk-XOR swizzled; img staged as 3 scalar f32 planes (conflict-free).
template <bool FIRST, bool LAST>
__global__ __launch_bounds__(512) void crf_iter(const float* __restrict__ unary,
                                                const float* __restrict__ img,
                                                const uint4* __restrict__ qin,
                                                uint4* __restrict__ qout,
                                                uint4* __restrict__ uh,
                                                float4* __restrict__ img4,
                                                float* __restrict__ outf) {
    __shared__ uint4 s_q4[NPIX * 4];      // 34,048 B (32 fp16 ch/pixel)
    __shared__ float s_im[3][NPIX];       //  6,384 B
    __shared__ float s_red[2][2][256];    //  4,096 B

    const int tid = threadIdx.x;
    const int hf  = tid >> 8;             // wave-uniform channel half
    const int lid = tid & 255;
    const int tx = lid & (TX - 1);
    const int ty = lid >> 5;
    const int bx = blockIdx.x * TX;
    const int by = blockIdx.y * TY;
    const int b  = blockIdx.z;

    const float* ubase = unary + (size_t)b * CNUM * HWP;

    // ---- staging ----
    if (FIRST) {
        const float* imgb = img + (size_t)b * 3 * HWP;
        for (int t = tid; t < NPIX; t += 512) {
            int r = t / LW, cc = t - r * LW;
            int gy = by + r - HALO, gx = bx + cc - HALO;
            bool ok = (gy >= 0) & (gy < HH) & (gx >= 0) & (gx < WW);
            int goff = ok ? gy * WW + gx : 0;
            float p0 = imgb[goff], p1 = imgb[HWP + goff], p2 = imgb[2 * HWP + goff];
            if (!ok) { p0 = 0.f; p1 = 0.f; p2 = 0.f; }
            s_im[0][t] = p0; s_im[1][t] = p1; s_im[2][t] = p2;
            bool interior = (r >= HALO) & (r < LH - HALO) & (cc >= HALO) & (cc < LW - HALO);
            if (interior) {
                float4 p; p.x = p0; p.y = p1; p.z = p2; p.w = 0.f;
                img4[(size_t)b * HWP + goff] = p;
            }

            float nu[32];
            float mm = -1e30f;
#pragma unroll
            for (int c = 0; c < CNUM; ++c) {
                nu[c] = -ubase[(size_t)c * HWP + goff];
                mm = fmaxf(mm, nu[c]);
            }
#pragma unroll
            for (int c = CNUM; c < 32; ++c) nu[c] = -65504.f;

            if (interior) {  // pre-pack -unary fp16, half-major
                uint4 u0, u1, u2, u3;
                u0.x = packh2(nu[0],  nu[1]);  u0.y = packh2(nu[2],  nu[3]);
                u0.z = packh2(nu[4],  nu[5]);  u0.w = packh2(nu[6],  nu[7]);
                u1.x = packh2(nu[8],  nu[9]);  u1.y = packh2(nu[10], nu[11]);
                u1.z = packh2(nu[12], nu[13]); u1.w = packh2(nu[14], nu[15]);
                u2.x = packh2(nu[16], nu[17]); u2.y = packh2(nu[18], nu[19]);
                u2.z = packh2(nu[20], nu[21]); u2.w = packh2(nu[22], nu[23]);
                u3.x = packh2(nu[24], nu[25]); u3.y = packh2(nu[26], nu[27]);
                u3.z = packh2(nu[28], nu[29]); u3.w = packh2(nu[30], nu[31]);
                uint4* w0 = uh + ((size_t)(b * 2 + 0) * HWP + goff) * 2;
                w0[0] = u0; w0[1] = u1;
                uint4* w1 = uh + ((size_t)(b * 2 + 1) * HWP + goff) * 2;
                w1[0] = u2; w1[1] = u3;
            }

            float v[32];
            float ss = 0.f;
#pragma unroll
            for (int c = 0; c < CNUM; ++c) { v[c] = __expf(nu[c] - mm); ss += v[c]; }
            float inv = ok ? 1.f / ss : 0.f;
#pragma unroll
            for (int c = 0; c < CNUM; ++c) v[c] *= inv;
#pragma unroll
            for (int c = CNUM; c < 32; ++c) v[c] = 0.f;
            const int swz = (t >> 1) & 3;
#pragma unroll
            for (int g = 0; g < 4; ++g) {
                uint4 pk;
                pk.x = packh2(v[8 * g + 0], v[8 * g + 1]);
                pk.y = packh2(v[8 * g + 2], v[8 * g + 3]);
                pk.z = packh2(v[8 * g + 4], v[8 * g + 5]);
                pk.w = packh2(v[8 * g + 6], v[8 * g + 7]);
                s_q4[t * 4 + (g ^ swz)] = pk;
            }
        }
    } else {
        for (int t = tid; t < NPIX; t += 512) {
            int r = t / LW, cc = t - r * LW;
            int gy = by + r - HALO, gx = bx + cc - HALO;
            bool ok = (gy >= 0) & (gy < HH) & (gx >= 0) & (gx < WW);
            int goff = ok ? gy * WW + gx : 0;
            float4 p = img4[(size_t)b * HWP + goff];
            if (!ok) { p.x = 0.f; p.y = 0.f; p.z = 0.f; }
            s_im[0][t] = p.x; s_im[1][t] = p.y; s_im[2][t] = p.z;
        }
#pragma unroll
        for (int h = 0; h < 2; ++h) {
            const uint4* qb = qin + (size_t)(b * 2 + h) * HWP * 2;
            for (int t = tid; t < NPIX; t += 512) {
                int r = t / LW, cc = t - r * LW;
                int gy = by + r - HALO, gx = bx + cc - HALO;
                bool ok = (gy >= 0) & (gy < HH) & (gx >= 0) & (gx < WW);
                int goff = ok ? gy * WW + gx : 0;
                uint4 v0 = qb[goff * 2 + 0];
                uint4 v1 = qb[goff * 2 + 1];
                if (!ok) {
                    v0.x = v0.y = v0.z = v0.w = 0u;
                    v1.x = v1.y = v1.z = v1.w = 0u;
                }
                const int swz = (t >> 1) & 3;
                s_q4[t * 4 + ((2 * h)     ^ swz)] = v0;
                s_q4[t * 4 + ((2 * h + 1) ^ swz)] = v1;
            }
        }
    }
    __syncthreads();

    // ---- 49-tap message passing: this half's 16 channels ----
    const int tc = (ty + HALO) * LW + (tx + HALO);
    const float c0 = s_im[0][tc];
    const float c1 = s_im[1][tc];
    const float c2 = s_im[2][tc];
    const int g0 = 2 * hf, g1 = 2 * hf + 1;

    float acc[16];
#pragma unroll
    for (int k = 0; k < 16; ++k) acc[k] = 0.f;

#pragma unroll
    for (int i = 0; i < KK; ++i) {
#pragma unroll
        for (int j = 0; j < KK; ++j) {
            const int t = (ty + i) * LW + (tx + j);
            float d0 = s_im[0][t] - c0;
            float d1 = s_im[1][t] - c1;
            float d2 = s_im[2][t] - c2;
            float dsq = d0 * d0 + d1 * d1 + d2 * d2;
            float w = (GW[i] * GW[j]) * (3.0f + 10.0f * __expf(dsq * -0.005f));
            const int t4 = t * 4;
            const int swz = (t >> 1) & 3;
            uint4 qa = s_q4[t4 + (g0 ^ swz)];
            uint4 qc = s_q4[t4 + (g1 ^ swz)];
            const unsigned* ua = &qa.x;
            const unsigned* uc = &qc.x;
#pragma unroll
            for (int k = 0; k < 4; ++k) {
                float2 f = unpkh2(ua[k]);
                acc[2 * k]     += w * f.x;
                acc[2 * k + 1] += w * f.y;
            }
#pragma unroll
            for (int k = 0; k < 4; ++k) {
                float2 f = unpkh2(uc[k]);
                acc[8 + 2 * k]     += w * f.x;
                acc[8 + 2 * k + 1] += w * f.y;
            }
        }
    }

    // ---- joined channel softmax (2-scalar LDS exchange) + store ----
    const int pix = (by + ty) * WW + (bx + tx);
    float l[16];
    if (FIRST) {
        const float* up = ubase + (size_t)hf * 16 * HWP + pix;
        if (hf == 0) {
#pragma unroll
            for (int k = 0; k < 16; ++k) l[k] = acc[k] - up[(size_t)k * HWP];
        } else {
#pragma unroll
            for (int k = 0; k < 13; ++k) l[k] = acc[k] - up[(size_t)k * HWP];
            l[13] = -1e30f; l[14] = -1e30f; l[15] = -1e30f;
        }
    } else {
        const uint4* up = uh + ((size_t)(b * 2 + hf) * HWP + pix) * 2;
        uint4 n0 = up[0], n1 = up[1];
        const unsigned* un0 = &n0.x;
        const unsigned* un1 = &n1.x;
#pragma unroll
        for (int k = 0; k < 4; ++k) {
            float2 f = unpkh2(un0[k]);
            l[2 * k]     = acc[2 * k]     + f.x;
            l[2 * k + 1] = acc[2 * k + 1] + f.y;
        }
#pragma unroll
        for (int k = 0; k < 4; ++k) {
            float2 f = unpkh2(un1[k]);
            l[8 + 2 * k]     = acc[8 + 2 * k]     + f.x;
            l[8 + 2 * k + 1] = acc[8 + 2 * k + 1] + f.y;
        }
    }
    float m_loc = l[0];
#pragma unroll
    for (int k = 1; k < 16; ++k) m_loc = fmaxf(m_loc, l[k]);
    s_red[0][hf][lid] = m_loc;
    __syncthreads();
    const float m = fmaxf(s_red[0][0][lid], s_red[0][1][lid]);
    float s_loc = 0.f;
#pragma unroll
    for (int k = 0; k < 16; ++k) { l[k] = __expf(l[k] - m); s_loc += l[k]; }
    s_red[1][hf][lid] = s_loc;
    __syncthreads();
    const float inv = 1.0f / (s_red[1][0][lid] + s_red[1][1][lid]);

    if (LAST) {
        float* qo = outf + (size_t)b * CNUM * HWP + pix;
        if (hf == 0) {
#pragma unroll
            for (int k = 0; k < 16; ++k) qo[(size_t)k * HWP] = l[k] * inv;
        } else {
#pragma unroll
            for (int k = 0; k < 13; ++k) qo[(size_t)(16 + k) * HWP] = l[k] * inv;
        }
    } else {
        uint4 p0, p1;
        p0.x = packh2(l[0] * inv,  l[1] * inv);
        p0.y = packh2(l[2] * inv,  l[3] * inv);
        p0.z = packh2(l[4] * inv,  l[5] * inv);
        p0.w = packh2(l[6] * inv,  l[7] * inv);
        p1.x = packh2(l[8] * inv,  l[9] * inv);
        p1.y = packh2(l[10] * inv, l[11] * inv);
        p1.z = packh2(l[12] * inv, l[13] * inv);
        p1.w = packh2(l[14] * inv, l[15] * inv);
        uint4* qo = qout + ((size_t)(b * 2 + hf) * HWP + pix) * 2;
        qo[0] = p0;
        qo[1] = p1;
    }
}

extern "C" void kernel_launch(void* const* d_in, const int* in_sizes, int n_in,
                              void* d_out, int out_size, void* d_ws, size_t ws_size,
                              hipStream_t stream) {
    const float* unary = (const float*)d_in[0];
    const float* img   = (const float*)d_in[1];
    // ws: qA (8.39MB) | qB (8.39MB) | uh (8.39MB) | img4 (2.10MB) = 27.3 MB
    const size_t QBYTES = (size_t)BB * 2 * HWP * 32;
    uint4*  qA   = (uint4*)d_ws;
    uint4*  qB   = (uint4*)((char*)d_ws + QBYTES);
    uint4*  uh   = (uint4*)((char*)d_ws + 2 * QBYTES);
    float4* img4 = (float4*)((char*)d_ws + 3 * QBYTES);
    float*  outf = (float*)d_out;

    dim3 grid(WW / TX, HH / TY, BB);
    crf_iter<true,  false><<<grid, 512, 0, stream>>>(unary, img, qB, qA, uh, img4, outf); // i1 -> qA
    crf_iter<false, false><<<grid, 512, 0, stream>>>(unary, img, qA, qB, uh, img4, outf); // i2
    crf_iter<false, false><<<grid, 512, 0, stream>>>(unary, img, qB, qA, uh, img4, outf); // i3
    crf_iter<false, false><<<grid, 512, 0, stream>>>(unary, img, qA, qB, uh, img4, outf); // i4
    crf_iter<false, true ><<<grid, 512, 0, stream>>>(unary, img, qB, qA, uh, img4, outf); // i5 -> d_out
}

// Round 7
// 108.649 us; speedup vs baseline: 2.6588x; 2.6588x over previous
//
#include <hip/hip_runtime.h>
#include <hip/hip_fp16.h>

#define CNUM 29
#define HH 256
#define WW 256
#define BB 2
#define KK 7
#define HALO 3
#define TX 32
#define TY 8
#define LW (TX + 2*HALO)   // 38
#define LH (TY + 2*HALO)   // 14
#define NPIX (LH*LW)       // 532
#define HWP (HH*WW)        // 65536

// 1-D normalized Gaussian, sigma=3.0, K=7 (exp(-d^2/18)/sum)
__device__ constexpr float GW[KK] = {
    0.106287146f, 0.140321912f, 0.165770643f, 0.175240699f,
    0.165770643f, 0.140321912f, 0.106287146f};

__device__ __forceinline__ unsigned packh2(float a, float b) {
    __half2 h = __floats2half2_rn(a, b);
    return *reinterpret_cast<unsigned*>(&h);
}
__device__ __forceinline__ float2 unpkh2(unsigned u) {
    __half2 h = *reinterpret_cast<__half2*>(&u);
    return __half22float2(h);
}

// One CRF iteration. 512 threads per 32x8 tile, TAP-SPLIT: waves 0-3 (tid<256)
// accumulate kernel rows i=0..3, waves 4-7 rows i=4..6; partials joined via an
// LDS [c][lid] buffer (aliasing s_q4 after the tap phase). All 29 channels per
// pixel -> round-4-proven LDS chunk layout + swizzle. Global q is fp16
// channel-last [pix][4 x uint4]: every 64B line written/read by one thread.
// uh = packed -unary fp16 (same layout), written in FIRST.
template <bool FIRST, bool LAST>
__global__ __launch_bounds__(512) void crf_iter(const float* __restrict__ unary,
                                                const float* __restrict__ img,
                                                const uint4* __restrict__ qin,
                                                uint4* __restrict__ qout,
                                                uint4* __restrict__ uh,
                                                float* __restrict__ outf) {
    __shared__ uint4 s_q4[NPIX * 4];      // 34,048 B; reused as partial[29][256] after taps
    __shared__ float s_im[3][NPIX];       //  6,384 B

    const int tid = threadIdx.x;
    const bool isA = tid < 256;           // wave-uniform half
    const int lid = tid & 255;
    const int tx = lid & (TX - 1);
    const int ty = lid >> 5;
    const int bx = blockIdx.x * TX;
    const int by = blockIdx.y * TY;
    const int b  = blockIdx.z;

    const float* ubase = unary + (size_t)b * CNUM * HWP;
    const float* imgb  = img + (size_t)b * 3 * HWP;

    // ---- stage: img (3 f32 planes) + q (fp16 chunks, XOR-swizzled) ----
    for (int t = tid; t < NPIX; t += 512) {
        int r = t / LW, cc = t - r * LW;
        int gy = by + r - HALO, gx = bx + cc - HALO;
        bool ok = (gy >= 0) & (gy < HH) & (gx >= 0) & (gx < WW);
        int goff = ok ? gy * WW + gx : 0;
        float i0 = imgb[goff], i1 = imgb[HWP + goff], i2 = imgb[2 * HWP + goff];
        if (!ok) { i0 = 0.f; i1 = 0.f; i2 = 0.f; }
        s_im[0][t] = i0; s_im[1][t] = i1; s_im[2][t] = i2;

        const int swz = (t >> 1) & 3;
        if (FIRST) {
            float nu[CNUM];
            float mm = -1e30f;
#pragma unroll
            for (int c = 0; c < CNUM; ++c) {
                nu[c] = -ubase[(size_t)c * HWP + goff];
                mm = fmaxf(mm, nu[c]);
            }
            bool interior = (r >= HALO) & (r < LH - HALO) & (cc >= HALO) & (cc < LW - HALO);
            if (interior) {  // pre-pack -unary fp16 (each pixel owned by one block)
                uint4* up = uh + ((size_t)b * HWP + goff) * 4;
                uint4 u0, u1, u2, u3;
                u0.x = packh2(nu[0],  nu[1]);  u0.y = packh2(nu[2],  nu[3]);
                u0.z = packh2(nu[4],  nu[5]);  u0.w = packh2(nu[6],  nu[7]);
                u1.x = packh2(nu[8],  nu[9]);  u1.y = packh2(nu[10], nu[11]);
                u1.z = packh2(nu[12], nu[13]); u1.w = packh2(nu[14], nu[15]);
                u2.x = packh2(nu[16], nu[17]); u2.y = packh2(nu[18], nu[19]);
                u2.z = packh2(nu[20], nu[21]); u2.w = packh2(nu[22], nu[23]);
                u3.x = packh2(nu[24], nu[25]); u3.y = packh2(nu[26], nu[27]);
                u3.z = packh2(nu[28], 0.f);    u3.w = 0u;
                up[0] = u0; up[1] = u1; up[2] = u2; up[3] = u3;
            }
            float ss = 0.f;
            float v[CNUM];
#pragma unroll
            for (int c = 0; c < CNUM; ++c) { v[c] = __expf(nu[c] - mm); ss += v[c]; }
            float inv = ok ? 1.f / ss : 0.f;
#pragma unroll
            for (int c = 0; c < CNUM; ++c) v[c] *= inv;
            uint4 p0, p1, p2, p3;
            p0.x = packh2(v[0],  v[1]);  p0.y = packh2(v[2],  v[3]);
            p0.z = packh2(v[4],  v[5]);  p0.w = packh2(v[6],  v[7]);
            p1.x = packh2(v[8],  v[9]);  p1.y = packh2(v[10], v[11]);
            p1.z = packh2(v[12], v[13]); p1.w = packh2(v[14], v[15]);
            p2.x = packh2(v[16], v[17]); p2.y = packh2(v[18], v[19]);
            p2.z = packh2(v[20], v[21]); p2.w = packh2(v[22], v[23]);
            p3.x = packh2(v[24], v[25]); p3.y = packh2(v[26], v[27]);
            p3.z = packh2(v[28], 0.f);   p3.w = 0u;
            s_q4[t * 4 + (0 ^ swz)] = p0;
            s_q4[t * 4 + (1 ^ swz)] = p1;
            s_q4[t * 4 + (2 ^ swz)] = p2;
            s_q4[t * 4 + (3 ^ swz)] = p3;
        } else {
            const uint4* qp = qin + ((size_t)b * HWP + goff) * 4;
            uint4 p0 = qp[0], p1 = qp[1], p2 = qp[2], p3 = qp[3];
            if (!ok) {
                p0.x = p0.y = p0.z = p0.w = 0u;
                p1.x = p1.y = p1.z = p1.w = 0u;
                p2.x = p2.y = p2.z = p2.w = 0u;
                p3.x = p3.y = p3.z = p3.w = 0u;
            }
            s_q4[t * 4 + (0 ^ swz)] = p0;
            s_q4[t * 4 + (1 ^ swz)] = p1;
            s_q4[t * 4 + (2 ^ swz)] = p2;
            s_q4[t * 4 + (3 ^ swz)] = p3;
        }
    }
    __syncthreads();

    // ---- tap phase (split rows between halves) ----
    const int tc = (ty + HALO) * LW + (tx + HALO);
    const float c0 = s_im[0][tc];
    const float c1 = s_im[1][tc];
    const float c2 = s_im[2][tc];

    float acc[CNUM];
#pragma unroll
    for (int c = 0; c < CNUM; ++c) acc[c] = 0.f;

#define TAP_BODY(ii)                                                        \
    {                                                                       \
        const int t = (ty + (ii)) * LW + (tx + j);                          \
        float d0 = s_im[0][t] - c0;                                         \
        float d1 = s_im[1][t] - c1;                                         \
        float d2 = s_im[2][t] - c2;                                         \
        float dsq = d0 * d0 + d1 * d1 + d2 * d2;                            \
        float w = (GW[(ii)] * GW[j]) * (3.0f + 10.0f * __expf(dsq * -0.005f)); \
        const int t4 = t * 4;                                               \
        const int swz = (t >> 1) & 3;                                       \
        uint4 q0 = s_q4[t4 + (0 ^ swz)];                                    \
        uint4 q1 = s_q4[t4 + (1 ^ swz)];                                    \
        uint4 q2 = s_q4[t4 + (2 ^ swz)];                                    \
        uint4 q3 = s_q4[t4 + (3 ^ swz)];                                    \
        const unsigned* u0 = &q0.x;                                         \
        const unsigned* u1 = &q1.x;                                         \
        const unsigned* u2 = &q2.x;                                         \
        _Pragma("unroll")                                                   \
        for (int k = 0; k < 4; ++k) {                                       \
            float2 f = unpkh2(u0[k]);                                       \
            acc[2 * k]     += w * f.x;                                      \
            acc[2 * k + 1] += w * f.y;                                      \
        }                                                                   \
        _Pragma("unroll")                                                   \
        for (int k = 0; k < 4; ++k) {                                       \
            float2 f = unpkh2(u1[k]);                                       \
            acc[8 + 2 * k]     += w * f.x;                                  \
            acc[8 + 2 * k + 1] += w * f.y;                                  \
        }                                                                   \
        _Pragma("unroll")                                                   \
        for (int k = 0; k < 4; ++k) {                                       \
            float2 f = unpkh2(u2[k]);                                       \
            acc[16 + 2 * k]     += w * f.x;                                 \
            acc[16 + 2 * k + 1] += w * f.y;                                 \
        }                                                                   \
        {                                                                   \
            float2 f = unpkh2(q3.x);                                        \
            acc[24] += w * f.x; acc[25] += w * f.y;                         \
            f = unpkh2(q3.y);                                               \
            acc[26] += w * f.x; acc[27] += w * f.y;                         \
            f = unpkh2(q3.z);                                               \
            acc[28] += w * f.x;                                             \
        }                                                                   \
    }

    if (isA) {
#pragma unroll
        for (int i = 0; i < 4; ++i)
#pragma unroll
            for (int j = 0; j < KK; ++j) TAP_BODY(i)
    } else {
#pragma unroll
        for (int i = 4; i < KK; ++i)
#pragma unroll
            for (int j = 0; j < KK; ++j) TAP_BODY(i)
    }
#undef TAP_BODY

    // ---- join partials: B writes [c][lid], A adds ----
    __syncthreads();                       // all s_q4 tap reads complete
    float* s_part = reinterpret_cast<float*>(s_q4);   // 29*256*4 = 29,696 B fits
    if (!isA) {
#pragma unroll
        for (int c = 0; c < CNUM; ++c) s_part[c * 256 + lid] = acc[c];
    }
    __syncthreads();

    if (isA) {
        const int pix = (by + ty) * WW + (bx + tx);
        float l[CNUM];
        if (FIRST) {
#pragma unroll
            for (int c = 0; c < CNUM; ++c)
                l[c] = acc[c] + s_part[c * 256 + lid] - ubase[(size_t)c * HWP + pix];
        } else {
            const uint4* up = uh + ((size_t)b * HWP + pix) * 4;
            uint4 n0 = up[0], n1 = up[1], n2 = up[2], n3 = up[3];
            const unsigned* w0 = &n0.x;
            const unsigned* w1 = &n1.x;
            const unsigned* w2 = &n2.x;
            float nu[CNUM];
#pragma unroll
            for (int k = 0; k < 4; ++k) {
                float2 f = unpkh2(w0[k]); nu[2 * k] = f.x; nu[2 * k + 1] = f.y;
            }
#pragma unroll
            for (int k = 0; k < 4; ++k) {
                float2 f = unpkh2(w1[k]); nu[8 + 2 * k] = f.x; nu[8 + 2 * k + 1] = f.y;
            }
#pragma unroll
            for (int k = 0; k < 4; ++k) {
                float2 f = unpkh2(w2[k]); nu[16 + 2 * k] = f.x; nu[16 + 2 * k + 1] = f.y;
            }
            { float2 f = unpkh2(n3.x); nu[24] = f.x; nu[25] = f.y; }
            { float2 f = unpkh2(n3.y); nu[26] = f.x; nu[27] = f.y; }
            { float2 f = unpkh2(n3.z); nu[28] = f.x; }
#pragma unroll
            for (int c = 0; c < CNUM; ++c)
                l[c] = acc[c] + s_part[c * 256 + lid] + nu[c];
        }
        float m = l[0];
#pragma unroll
        for (int c = 1; c < CNUM; ++c) m = fmaxf(m, l[c]);
        float ss = 0.f;
#pragma unroll
        for (int c = 0; c < CNUM; ++c) { l[c] = __expf(l[c] - m); ss += l[c]; }
        float inv = 1.0f / ss;

        if (LAST) {
            float* qo = outf + (size_t)b * CNUM * HWP + pix;
#pragma unroll
            for (int c = 0; c < CNUM; ++c) qo[(size_t)c * HWP] = l[c] * inv;
        } else {
            uint4 p0, p1, p2, p3;
            p0.x = packh2(l[0] * inv,  l[1] * inv);
            p0.y = packh2(l[2] * inv,  l[3] * inv);
            p0.z = packh2(l[4] * inv,  l[5] * inv);
            p0.w = packh2(l[6] * inv,  l[7] * inv);
            p1.x = packh2(l[8] * inv,  l[9] * inv);
            p1.y = packh2(l[10] * inv, l[11] * inv);
            p1.z = packh2(l[12] * inv, l[13] * inv);
            p1.w = packh2(l[14] * inv, l[15] * inv);
            p2.x = packh2(l[16] * inv, l[17] * inv);
            p2.y = packh2(l[18] * inv, l[19] * inv);
            p2.z = packh2(l[20] * inv, l[21] * inv);
            p2.w = packh2(l[22] * inv, l[23] * inv);
            p3.x = packh2(l[24] * inv, l[25] * inv);
            p3.y = packh2(l[26] * inv, l[27] * inv);
            p3.z = packh2(l[28] * inv, 0.f);
            p3.w = 0u;
            uint4* qo = qout + ((size_t)b * HWP + pix) * 4;
            qo[0] = p0; qo[1] = p1; qo[2] = p2; qo[3] = p3;
        }
    }
}

extern "C" void kernel_launch(void* const* d_in, const int* in_sizes, int n_in,
                              void* d_out, int out_size, void* d_ws, size_t ws_size,
                              hipStream_t stream) {
    const float* unary = (const float*)d_in[0];
    const float* img   = (const float*)d_in[1];
    // ws: qA (8.39MB) | qB (8.39MB) | uh (8.39MB) = 25.2 MB
    const size_t QBYTES = (size_t)BB * HWP * 64;
    uint4* qA = (uint4*)d_ws;
    uint4* qB = (uint4*)((char*)d_ws + QBYTES);
    uint4* uh = (uint4*)((char*)d_ws + 2 * QBYTES);
    float* outf = (float*)d_out;

    dim3 grid(WW / TX, HH / TY, BB);
    crf_iter<true,  false><<<grid, 512, 0, stream>>>(unary, img, qB, qA, uh, outf); // i1 -> qA
    crf_iter<false, false><<<grid, 512, 0, stream>>>(unary, img, qA, qB, uh, outf); // i2
    crf_iter<false, false><<<grid, 512, 0, stream>>>(unary, img, qB, qA, uh, outf); // i3
    crf_iter<false, false><<<grid, 512, 0, stream>>>(unary, img, qA, qB, uh, outf); // i4
    crf_iter<false, true ><<<grid, 512, 0, stream>>>(unary, img, qB, qA, uh, outf); // i5 -> d_out
}

// Round 8
// 100.041 us; speedup vs baseline: 2.8876x; 1.0860x over previous
//
#include <hip/hip_runtime.h>
#include <hip/hip_fp16.h>

#define CNUM 29
#define HH 256
#define WW 256
#define BB 2
#define KK 7
#define HALO 3
#define TX 32
#define TY 4
#define LW (TX + 2*HALO)   // 38
#define LH (TY + 2*HALO)   // 10
#define NPIX (LH*LW)       // 380
#define HWP (HH*WW)        // 65536

// 1-D normalized Gaussian, sigma=3.0, K=7 (exp(-d^2/18)/sum)
__device__ constexpr float GW[KK] = {
    0.106287146f, 0.140321912f, 0.165770643f, 0.175240699f,
    0.165770643f, 0.140321912f, 0.106287146f};

__device__ __forceinline__ unsigned packh2(float a, float b) {
    __half2 h = __floats2half2_rn(a, b);
    return *reinterpret_cast<unsigned*>(&h);
}
__device__ __forceinline__ float2 unpkh2(unsigned u) {
    __half2 h = *reinterpret_cast<__half2*>(&u);
    return __half22float2(h);
}

// One CRF iteration. 256 threads per 32x4 tile (4 blocks/CU -> 4 independent
// barrier domains), TAP-SPLIT: threads 0-127 accumulate kernel rows i=0..3,
// threads 128-255 rows i=4..6; partials joined via LDS [c][lid] (aliasing
// s_q4 after taps). Global q is fp16 channel-last [pix][4 x uint4] (one 64B
// line per pixel per thread). uh = packed -unary fp16, written in FIRST.
template <bool FIRST, bool LAST>
__global__ __launch_bounds__(256) void crf_iter(const float* __restrict__ unary,
                                                const float* __restrict__ img,
                                                const uint4* __restrict__ qin,
                                                uint4* __restrict__ qout,
                                                uint4* __restrict__ uh,
                                                float* __restrict__ outf) {
    __shared__ uint4 s_q4[NPIX * 4];      // 24,320 B; reused as partial[29][128]
    __shared__ float s_im[3][NPIX];       //  4,560 B

    const int tid = threadIdx.x;
    const bool isA = tid < 128;           // wave-uniform half
    const int lid = tid & 127;
    const int tx = lid & (TX - 1);
    const int ty = lid >> 5;              // 0..3
    const int bx = blockIdx.x * TX;
    const int by = blockIdx.y * TY;
    const int b  = blockIdx.z;

    const float* ubase = unary + (size_t)b * CNUM * HWP;
    const float* imgb  = img + (size_t)b * 3 * HWP;

    // ---- stage: img (3 f32 planes) + q (fp16 chunks, XOR-swizzled) ----
    for (int t = tid; t < NPIX; t += 256) {
        int r = t / LW, cc = t - r * LW;
        int gy = by + r - HALO, gx = bx + cc - HALO;
        bool ok = (gy >= 0) & (gy < HH) & (gx >= 0) & (gx < WW);
        int goff = ok ? gy * WW + gx : 0;
        float i0 = imgb[goff], i1 = imgb[HWP + goff], i2 = imgb[2 * HWP + goff];
        if (!ok) { i0 = 0.f; i1 = 0.f; i2 = 0.f; }
        s_im[0][t] = i0; s_im[1][t] = i1; s_im[2][t] = i2;

        const int swz = (t >> 1) & 3;
        if (FIRST) {
            float nu[CNUM];
            float mm = -1e30f;
#pragma unroll
            for (int c = 0; c < CNUM; ++c) {
                nu[c] = -ubase[(size_t)c * HWP + goff];
                mm = fmaxf(mm, nu[c]);
            }
            bool interior = (r >= HALO) & (r < LH - HALO) & (cc >= HALO) & (cc < LW - HALO);
            if (interior) {  // pre-pack -unary fp16 (each pixel owned by one block)
                uint4* up = uh + ((size_t)b * HWP + goff) * 4;
                uint4 u0, u1, u2, u3;
                u0.x = packh2(nu[0],  nu[1]);  u0.y = packh2(nu[2],  nu[3]);
                u0.z = packh2(nu[4],  nu[5]);  u0.w = packh2(nu[6],  nu[7]);
                u1.x = packh2(nu[8],  nu[9]);  u1.y = packh2(nu[10], nu[11]);
                u1.z = packh2(nu[12], nu[13]); u1.w = packh2(nu[14], nu[15]);
                u2.x = packh2(nu[16], nu[17]); u2.y = packh2(nu[18], nu[19]);
                u2.z = packh2(nu[20], nu[21]); u2.w = packh2(nu[22], nu[23]);
                u3.x = packh2(nu[24], nu[25]); u3.y = packh2(nu[26], nu[27]);
                u3.z = packh2(nu[28], 0.f);    u3.w = 0u;
                up[0] = u0; up[1] = u1; up[2] = u2; up[3] = u3;
            }
            float ss = 0.f;
            float v[CNUM];
#pragma unroll
            for (int c = 0; c < CNUM; ++c) { v[c] = __expf(nu[c] - mm); ss += v[c]; }
            float inv = ok ? 1.f / ss : 0.f;
#pragma unroll
            for (int c = 0; c < CNUM; ++c) v[c] *= inv;
            uint4 p0, p1, p2, p3;
            p0.x = packh2(v[0],  v[1]);  p0.y = packh2(v[2],  v[3]);
            p0.z = packh2(v[4],  v[5]);  p0.w = packh2(v[6],  v[7]);
            p1.x = packh2(v[8],  v[9]);  p1.y = packh2(v[10], v[11]);
            p1.z = packh2(v[12], v[13]); p1.w = packh2(v[14], v[15]);
            p2.x = packh2(v[16], v[17]); p2.y = packh2(v[18], v[19]);
            p2.z = packh2(v[20], v[21]); p2.w = packh2(v[22], v[23]);
            p3.x = packh2(v[24], v[25]); p3.y = packh2(v[26], v[27]);
            p3.z = packh2(v[28], 0.f);   p3.w = 0u;
            s_q4[t * 4 + (0 ^ swz)] = p0;
            s_q4[t * 4 + (1 ^ swz)] = p1;
            s_q4[t * 4 + (2 ^ swz)] = p2;
            s_q4[t * 4 + (3 ^ swz)] = p3;
        } else {
            const uint4* qp = qin + ((size_t)b * HWP + goff) * 4;
            uint4 p0 = qp[0], p1 = qp[1], p2 = qp[2], p3 = qp[3];
            if (!ok) {
                p0.x = p0.y = p0.z = p0.w = 0u;
                p1.x = p1.y = p1.z = p1.w = 0u;
                p2.x = p2.y = p2.z = p2.w = 0u;
                p3.x = p3.y = p3.z = p3.w = 0u;
            }
            s_q4[t * 4 + (0 ^ swz)] = p0;
            s_q4[t * 4 + (1 ^ swz)] = p1;
            s_q4[t * 4 + (2 ^ swz)] = p2;
            s_q4[t * 4 + (3 ^ swz)] = p3;
        }
    }
    __syncthreads();

    // ---- tap phase (kernel rows split between halves) ----
    const int tc = (ty + HALO) * LW + (tx + HALO);
    const float c0 = s_im[0][tc];
    const float c1 = s_im[1][tc];
    const float c2 = s_im[2][tc];

    float acc[CNUM];
#pragma unroll
    for (int c = 0; c < CNUM; ++c) acc[c] = 0.f;

#define TAP_BODY(ii)                                                        \
    {                                                                       \
        const int t = (ty + (ii)) * LW + (tx + j);                          \
        float d0 = s_im[0][t] - c0;                                         \
        float d1 = s_im[1][t] - c1;                                         \
        float d2 = s_im[2][t] - c2;                                         \
        float dsq = d0 * d0 + d1 * d1 + d2 * d2;                            \
        float w = (GW[(ii)] * GW[j]) * (3.0f + 10.0f * __expf(dsq * -0.005f)); \
        const int t4 = t * 4;                                               \
        const int swz = (t >> 1) & 3;                                       \
        uint4 q0 = s_q4[t4 + (0 ^ swz)];                                    \
        uint4 q1 = s_q4[t4 + (1 ^ swz)];                                    \
        uint4 q2 = s_q4[t4 + (2 ^ swz)];                                    \
        uint4 q3 = s_q4[t4 + (3 ^ swz)];                                    \
        const unsigned* u0 = &q0.x;                                         \
        const unsigned* u1 = &q1.x;                                         \
        const unsigned* u2 = &q2.x;                                         \
        _Pragma("unroll")                                                   \
        for (int k = 0; k < 4; ++k) {                                       \
            float2 f = unpkh2(u0[k]);                                       \
            acc[2 * k]     += w * f.x;                                      \
            acc[2 * k + 1] += w * f.y;                                      \
        }                                                                   \
        _Pragma("unroll")                                                   \
        for (int k = 0; k < 4; ++k) {                                       \
            float2 f = unpkh2(u1[k]);                                       \
            acc[8 + 2 * k]     += w * f.x;                                  \
            acc[8 + 2 * k + 1] += w * f.y;                                  \
        }                                                                   \
        _Pragma("unroll")                                                   \
        for (int k = 0; k < 4; ++k) {                                       \
            float2 f = unpkh2(u2[k]);                                       \
            acc[16 + 2 * k]     += w * f.x;                                 \
            acc[16 + 2 * k + 1] += w * f.y;                                 \
        }                                                                   \
        {                                                                   \
            float2 f = unpkh2(q3.x);                                        \
            acc[24] += w * f.x; acc[25] += w * f.y;                         \
            f = unpkh2(q3.y);                                               \
            acc[26] += w * f.x; acc[27] += w * f.y;                         \
            f = unpkh2(q3.z);                                               \
            acc[28] += w * f.x;                                             \
        }                                                                   \
    }

    if (isA) {
#pragma unroll
        for (int i = 0; i < 4; ++i)
#pragma unroll
            for (int j = 0; j < KK; ++j) TAP_BODY(i)
    } else {
#pragma unroll
        for (int i = 4; i < KK; ++i)
#pragma unroll
            for (int j = 0; j < KK; ++j) TAP_BODY(i)
    }
#undef TAP_BODY

    // ---- join partials: B writes [c][lid], A adds ----
    __syncthreads();                       // all s_q4 tap reads complete
    float* s_part = reinterpret_cast<float*>(s_q4);   // 29*128*4 = 14,848 B fits
    if (!isA) {
#pragma unroll
        for (int c = 0; c < CNUM; ++c) s_part[c * 128 + lid] = acc[c];
    }
    __syncthreads();

    if (isA) {
        const int pix = (by + ty) * WW + (bx + tx);
        float l[CNUM];
        if (FIRST) {
#pragma unroll
            for (int c = 0; c < CNUM; ++c)
                l[c] = acc[c] + s_part[c * 128 + lid] - ubase[(size_t)c * HWP + pix];
        } else {
            const uint4* up = uh + ((size_t)b * HWP + pix) * 4;
            uint4 n0 = up[0], n1 = up[1], n2 = up[2], n3 = up[3];
            const unsigned* w0 = &n0.x;
            const unsigned* w1 = &n1.x;
            const unsigned* w2 = &n2.x;
            float nu[CNUM];
#pragma unroll
            for (int k = 0; k < 4; ++k) {
                float2 f = unpkh2(w0[k]); nu[2 * k] = f.x; nu[2 * k + 1] = f.y;
            }
#pragma unroll
            for (int k = 0; k < 4; ++k) {
                float2 f = unpkh2(w1[k]); nu[8 + 2 * k] = f.x; nu[8 + 2 * k + 1] = f.y;
            }
#pragma unroll
            for (int k = 0; k < 4; ++k) {
                float2 f = unpkh2(w2[k]); nu[16 + 2 * k] = f.x; nu[16 + 2 * k + 1] = f.y;
            }
            { float2 f = unpkh2(n3.x); nu[24] = f.x; nu[25] = f.y; }
            { float2 f = unpkh2(n3.y); nu[26] = f.x; nu[27] = f.y; }
            { float2 f = unpkh2(n3.z); nu[28] = f.x; }
#pragma unroll
            for (int c = 0; c < CNUM; ++c)
                l[c] = acc[c] + s_part[c * 128 + lid] + nu[c];
        }
        float m = l[0];
#pragma unroll
        for (int c = 1; c < CNUM; ++c) m = fmaxf(m, l[c]);
        float ss = 0.f;
#pragma unroll
        for (int c = 0; c < CNUM; ++c) { l[c] = __expf(l[c] - m); ss += l[c]; }
        float inv = 1.0f / ss;

        if (LAST) {
            float* qo = outf + (size_t)b * CNUM * HWP + pix;
#pragma unroll
            for (int c = 0; c < CNUM; ++c) qo[(size_t)c * HWP] = l[c] * inv;
        } else {
            uint4 p0, p1, p2, p3;
            p0.x = packh2(l[0] * inv,  l[1] * inv);
            p0.y = packh2(l[2] * inv,  l[3] * inv);
            p0.z = packh2(l[4] * inv,  l[5] * inv);
            p0.w = packh2(l[6] * inv,  l[7] * inv);
            p1.x = packh2(l[8] * inv,  l[9] * inv);
            p1.y = packh2(l[10] * inv, l[11] * inv);
            p1.z = packh2(l[12] * inv, l[13] * inv);
            p1.w = packh2(l[14] * inv, l[15] * inv);
            p2.x = packh2(l[16] * inv, l[17] * inv);
            p2.y = packh2(l[18] * inv, l[19] * inv);
            p2.z = packh2(l[20] * inv, l[21] * inv);
            p2.w = packh2(l[22] * inv, l[23] * inv);
            p3.x = packh2(l[24] * inv, l[25] * inv);
            p3.y = packh2(l[26] * inv, l[27] * inv);
            p3.z = packh2(l[28] * inv, 0.f);
            p3.w = 0u;
            uint4* qo = qout + ((size_t)b * HWP + pix) * 4;
            qo[0] = p0; qo[1] = p1; qo[2] = p2; qo[3] = p3;
        }
    }
}

extern "C" void kernel_launch(void* const* d_in, const int* in_sizes, int n_in,
                              void* d_out, int out_size, void* d_ws, size_t ws_size,
                              hipStream_t stream) {
    const float* unary = (const float*)d_in[0];
    const float* img   = (const float*)d_in[1];
    // ws: qA (8.39MB) | qB (8.39MB) | uh (8.39MB) = 25.2 MB
    const size_t QBYTES = (size_t)BB * HWP * 64;
    uint4* qA = (uint4*)d_ws;
    uint4* qB = (uint4*)((char*)d_ws + QBYTES);
    uint4* uh = (uint4*)((char*)d_ws + 2 * QBYTES);
    float* outf = (float*)d_out;

    dim3 grid(WW / TX, HH / TY, BB);   // (8, 64, 2) = 1024 blocks
    crf_iter<true,  false><<<grid, 256, 0, stream>>>(unary, img, qB, qA, uh, outf); // i1 -> qA
    crf_iter<false, false><<<grid, 256, 0, stream>>>(unary, img, qA, qB, uh, outf); // i2
    crf_iter<false, false><<<grid, 256, 0, stream>>>(unary, img, qB, qA, uh, outf); // i3
    crf_iter<false, false><<<grid, 256, 0, stream>>>(unary, img, qA, qB, uh, outf); // i4
    crf_iter<false, true ><<<grid, 256, 0, stream>>>(unary, img, qB, qA, uh, outf); // i5 -> d_out
}